// Round 9
// baseline (97.228 us; speedup 1.0000x reference)
//
#include <hip/hip_runtime.h>
#include <hip/hip_bf16.h>
#include <stdint.h>

#define K_DIM 128
#define N_X   8192      // columns of x (the "n" / M dimension)
#define N_WO  8192      // 64*128 flattened (w,o) -> GEMM N dimension
#define OUT_TOTAL (8192UL * 64UL * 128UL)
#define CHUNKS_PER_PANEL 131072   // (8192/16 tiles) * 4 ksteps * 64 lanes

typedef __attribute__((ext_vector_type(8))) short short8;   // 8 bf16 = 4 VGPR
typedef __attribute__((ext_vector_type(4))) float f32x4;

__device__ inline unsigned short f2bf(float f) {
    union { float f; unsigned u; } v; v.f = f;
    unsigned u = v.u;
    u += 0x7fffu + ((u >> 16) & 1u);   // round-to-nearest-even
    return (unsigned short)(u >> 16);
}

// Transpose+convert W[128][8192] f32 (k-major, inner contiguous) into MFMA
// fragment-linear bf16 blocks. Chunk cc = ((t*4 + ks)*64 + l), elem j:
//   W[ks*32 + (l>>4)*8 + j][t*16 + (l&15)]
__global__ __launch_bounds__(256) void prep_w(const float* __restrict__ W,
                                              uint4* __restrict__ Q) {
    int cc = blockIdx.x * 256 + threadIdx.x;   // 0 .. 131071
    int l  = cc & 63;
    int ks = (cc >> 6) & 3;
    int t  = cc >> 8;
    int m  = t * 16 + (l & 15);
    int k0 = ks * 32 + ((l >> 4) << 3);
    const float* p = W + (size_t)k0 * N_X + m;
    unsigned short h[8];
#pragma unroll
    for (int j = 0; j < 8; ++j) h[j] = f2bf(p[(size_t)j * N_X]);
    uint4 q;
    q.x = (unsigned)h[0] | ((unsigned)h[1] << 16);
    q.y = (unsigned)h[2] | ((unsigned)h[3] << 16);
    q.z = (unsigned)h[4] | ((unsigned)h[5] << 16);
    q.w = (unsigned)h[6] | ((unsigned)h[7] << 16);
    Q[cc] = q;
}

// Row-slab sweep GEMM (r5 structure): block = 32 output rows x ALL 8192 wo,
// 512 threads = 8 waves; wave w covers wo-tiles {it*32 + w*4 .. +3} per iter.
// x-fragments converted INLINE from f32 (once per block, 64 scalar loads per
// lane); W streams from the pre-converted bf16 fragment panel (L2-resident).
// Output stores are NON-TEMPORAL: the write stream must not evict the W
// panel from L2 (write-allocate churn -> HBM B-refetch mixed into the write
// stream -> read/write turnaround penalty). Stores here are 64B-contiguous
// row-segments with adjacent segments issued back-to-back, so HBM handles
// them efficiently without L2 line assembly (unlike the r1/r2 4B-scatter).
// Operand-SWAPPED mfma: acc = mfma(Wfrag, xfrag) => D[wo][n]; lane holds 4
// consecutive wo at one n -> contiguous dwordx4 stores.
__global__ __launch_bounds__(512, 2) void gemm_sweep(const float* __restrict__ x,
                                                     const short8* __restrict__ B,
                                                     const float* __restrict__ bias,
                                                     float* __restrict__ out) {
    int bid = blockIdx.x;
    // bijective XCD swizzle (256 % 8 == 0): 32 consecutive slabs per XCD
    int swz = (bid & 7) * 32 + (bid >> 3);
    int n0  = swz * 32;

    int tid  = threadIdx.x;
    int lane = tid & 63;
    int w    = tid >> 6;               // 0..7
    int cl = lane & 15, rg = (lane >> 4) << 2;

    // x fragments for this block's 2 row-tiles, all 4 K-steps: convert from
    // raw f32 x (same element mapping prep_w uses). Once per block.
    short8 xf[2][4];
#pragma unroll
    for (int i = 0; i < 2; ++i) {
        int m = (swz * 2 + i) * 16 + cl;
#pragma unroll
        for (int ks = 0; ks < 4; ++ks) {
            int k0 = ks * 32 + ((lane >> 4) << 3);
            const float* p = x + (size_t)k0 * N_X + m;
            unsigned short h[8];
#pragma unroll
            for (int j = 0; j < 8; ++j) h[j] = f2bf(p[(size_t)j * N_X]);
            union { uint4 q; short8 s; } u;
            u.q.x = (unsigned)h[0] | ((unsigned)h[1] << 16);
            u.q.y = (unsigned)h[2] | ((unsigned)h[3] << 16);
            u.q.z = (unsigned)h[4] | ((unsigned)h[5] << 16);
            u.q.w = (unsigned)h[6] | ((unsigned)h[7] << 16);
            xf[i][ks] = u.s;
        }
    }

    // bias: (tj*16+rg) mod 128 is iteration-invariant per (w,j) since
    // it*32 % 8 == 0 -> hoist 4 premultiplied float4s into registers.
    f32x4 bvs[4];
#pragma unroll
    for (int j = 0; j < 4; ++j) {
        const f32x4 bv = *(const f32x4*)(bias + ((((w * 4 + j) & 7) << 4) + rg));
        bvs[j].x = 128.0f * bv.x;  bvs[j].y = 128.0f * bv.y;
        bvs[j].z = 128.0f * bv.z;  bvs[j].w = 128.0f * bv.w;
    }

    float* out0 = out + (size_t)n0 * N_WO;
    float* out1 = out0 + 16 * N_WO;

#pragma unroll 2
    for (int it = 0; it < 16; ++it) {
        int tj0 = it * 32 + w * 4;     // this wave's 4 wo-tiles this iteration
        short8 wf[4][4];
#pragma unroll
        for (int j = 0; j < 4; ++j)
#pragma unroll
            for (int ks = 0; ks < 4; ++ks)
                wf[j][ks] = B[(size_t)((tj0 + j) * 4 + ks) * 64 + lane];

        f32x4 acc[2][4] = {};
#pragma unroll
        for (int ks = 0; ks < 4; ++ks)
#pragma unroll
            for (int i = 0; i < 2; ++i)
#pragma unroll
                for (int j = 0; j < 4; ++j)
                    acc[i][j] = __builtin_amdgcn_mfma_f32_16x16x32_bf16(
                        wf[j][ks], xf[i][ks], acc[i][j], 0, 0, 0); // D[wo][n]

        // stores: col(lane&15)=n within tile i, row((lane>>4)*4+reg)=wo
        float* po0 = out0 + (size_t)cl * N_WO;
        float* po1 = out1 + (size_t)cl * N_WO;
#pragma unroll
        for (int j = 0; j < 4; ++j) {
            int wo = (tj0 + j) * 16 + rg;
            f32x4 v0 = acc[0][j], v1 = acc[1][j];
            v0.x += bvs[j].x; v0.y += bvs[j].y; v0.z += bvs[j].z; v0.w += bvs[j].w;
            v1.x += bvs[j].x; v1.y += bvs[j].y; v1.z += bvs[j].z; v1.w += bvs[j].w;
            __builtin_nontemporal_store(v0, (f32x4*)(po0 + wo));
            __builtin_nontemporal_store(v1, (f32x4*)(po1 + wo));
        }
    }
}

// Correctness fallback if d_ws is too small for the transposed panel.
__global__ __launch_bounds__(256) void naive_kernel(const float* __restrict__ x,
                                                    const float* __restrict__ wgt,
                                                    const float* __restrict__ bias,
                                                    float* __restrict__ out) {
    size_t idx = (size_t)blockIdx.x * 256 + threadIdx.x;
    if (idx >= OUT_TOTAL) return;
    int n    = (int)(idx >> 13);
    int ncol = (int)(idx & 8191);
    float s = 0.f;
    for (int i = 0; i < K_DIM; ++i)
        s += x[(size_t)i * N_X + n] * wgt[(size_t)i * N_WO + ncol];
    out[idx] = s + 128.0f * bias[ncol & 127];
}

extern "C" void kernel_launch(void* const* d_in, const int* in_sizes, int n_in,
                              void* d_out, int out_size, void* d_ws, size_t ws_size,
                              hipStream_t stream) {
    const float* x    = (const float*)d_in[0];   // [128][8192]
    const float* wgt  = (const float*)d_in[1];   // [128][64*128]
    const float* bias = (const float*)d_in[2];   // [128]
    float* out = (float*)d_out;

    if (ws_size >= 2u * 1024u * 1024u) {
        uint4* wsB = (uint4*)d_ws;                    // 2 MiB: W frag bf16
        prep_w<<<512, 256, 0, stream>>>(wgt, wsB);
        gemm_sweep<<<256, 512, 0, stream>>>(x, (const short8*)wsB, bias, out);
    } else {
        naive_kernel<<<(unsigned)((OUT_TOTAL + 255) / 256), 256, 0, stream>>>(
            x, wgt, bias, out);
    }
}

// Round 10
// 77.933 us; speedup vs baseline: 1.2476x; 1.2476x over previous
//
#include <hip/hip_runtime.h>
#include <hip/hip_bf16.h>
#include <stdint.h>

#define K_DIM 128
#define N_X   8192      // columns of x (the "n" / M dimension)
#define N_WO  8192      // 64*128 flattened (w,o) -> GEMM N dimension
#define OUT_TOTAL (8192UL * 64UL * 128UL)
#define CHUNKS_PER_PANEL 131072   // 256 tiles * 8 ksteps * 64 lanes

typedef __attribute__((ext_vector_type(8)))  short short8;   // 8 bf16 = 4 VGPR
typedef __attribute__((ext_vector_type(4)))  float f32x4;
typedef __attribute__((ext_vector_type(16))) float f32x16;

__device__ inline unsigned short f2bf(float f) {
    union { float f; unsigned u; } v; v.f = f;
    unsigned u = v.u;
    u += 0x7fffu + ((u >> 16) & 1u);   // round-to-nearest-even
    return (unsigned short)(u >> 16);
}

// Transpose+convert BOTH panels P[128][8192] f32 (k-major, inner contiguous)
// into mfma_f32_32x32x16_bf16 fragment-linear bf16 blocks.
// Chunk cc = ((t*8 + ks)*64 + l), elem j (0..7):
//   P[ks*16 + (l>>5)*8 + j][t*32 + (l&31)]
// (A and B fragments of 32x32x16 share this layout: m/n = lane&31,
//  k = (lane>>5)*8 + j — the 32-wide analog of the verified 16x16 mapping.)
__global__ __launch_bounds__(256) void prep_frag2(const float* __restrict__ X,
                                                  const float* __restrict__ W,
                                                  uint4* __restrict__ Q) {
    int c  = blockIdx.x * 256 + threadIdx.x;   // 0 .. 262143
    int cc = c & (CHUNKS_PER_PANEL - 1);
    const float* P = (c >= CHUNKS_PER_PANEL) ? W : X;
    int l  = cc & 63;
    int ks = (cc >> 6) & 7;
    int t  = cc >> 9;
    int m  = t * 32 + (l & 31);
    int k0 = ks * 16 + ((l >> 5) << 3);
    const float* p = P + (size_t)k0 * N_X + m;
    unsigned short h[8];
#pragma unroll
    for (int j = 0; j < 8; ++j) h[j] = f2bf(p[(size_t)j * N_X]);
    uint4 q;
    q.x = (unsigned)h[0] | ((unsigned)h[1] << 16);
    q.y = (unsigned)h[2] | ((unsigned)h[3] << 16);
    q.z = (unsigned)h[4] | ((unsigned)h[5] << 16);
    q.w = (unsigned)h[6] | ((unsigned)h[7] << 16);
    Q[c] = q;
}

// Row-slab sweep GEMM with FULL-CACHE-LINE stores via 32x32x16 MFMA.
// Block = 32 output rows (n) x ALL 8192 wo, 512 threads = 8 waves.
// Wave w handles wo-tiles {it*16 + 2w, +1} per iteration (16 iters).
// NON-swapped mfma: acc = mfma(xf, wf) => D[n][wo] with col=lane&31 = wo,
// row = (reg&3)+8*(reg>>2)+4*(lane>>5) = n  (m74/m101-verified layout).
// => every store_dword: 64 lanes cover 2 rows x 128B CONTIGUOUS = full L2
// lines per instruction (vs 64B half-lines with the 16x16 layout). This is
// the fill kernel's write shape, with zero shuffle/LDS cost.
__global__ __launch_bounds__(512, 2) void gemm_sweep32(const short8* __restrict__ A,
                                                       const short8* __restrict__ B,
                                                       const float* __restrict__ bias,
                                                       float* __restrict__ out) {
    int bid = blockIdx.x;
    // bijective XCD swizzle (256 % 8 == 0): 32 consecutive slabs per XCD
    int swz = (bid & 7) * 32 + (bid >> 3);
    int n0  = swz * 32;

    int tid  = threadIdx.x;
    int lane = tid & 63;
    int w    = tid >> 6;               // 0..7
    int cl   = lane & 31;              // wo within tile (store col), m in frag
    int hi   = lane >> 5;

    // x fragments for this block's one 32-row tile, all 8 K-steps (VGPRs)
    short8 xf[8];
#pragma unroll
    for (int ks = 0; ks < 8; ++ks)
        xf[ks] = A[(size_t)(swz * 8 + ks) * 64 + lane];

    // bias: tile index (it*16 + 2w + j) mod 4 = (2w+j)&3 — wave-invariant.
    // j=0 -> even slot {0,2}, j=1 -> odd slot {1,3}, selected by w&1.
    float b0 = 128.0f * bias[cl];            // tiles ≡ 0 (mod 4)
    float b1 = 128.0f * bias[32 + cl];       // ≡ 1
    float b2 = 128.0f * bias[64 + cl];       // ≡ 2
    float b3 = 128.0f * bias[96 + cl];       // ≡ 3
    float bj0 = (w & 1) ? b2 : b0;
    float bj1 = (w & 1) ? b3 : b1;

    // per-lane store base: rows n0 + 4*hi + (reg&3) + 8*(reg>>2), col cl
    float* pbase = out + (size_t)(n0 + 4 * hi) * N_WO + cl;

    for (int it = 0; it < 16; ++it) {
        int t0 = it * 16 + w * 2;      // wave's 2 wo-tiles this iteration
        short8 wfa[8], wfb[8];
#pragma unroll
        for (int ks = 0; ks < 8; ++ks) {
            wfa[ks] = B[(size_t)(t0 * 8 + ks) * 64 + lane];
            wfb[ks] = B[(size_t)((t0 + 1) * 8 + ks) * 64 + lane];
        }
        f32x16 acc0 = {}, acc1 = {};
#pragma unroll
        for (int ks = 0; ks < 8; ++ks) {
            acc0 = __builtin_amdgcn_mfma_f32_32x32x16_bf16(xf[ks], wfa[ks], acc0, 0, 0, 0);
            acc1 = __builtin_amdgcn_mfma_f32_32x32x16_bf16(xf[ks], wfb[ks], acc1, 0, 0, 0);
        }

        // stores: reg r -> row (r&3)+8*(r>>2) (+4*hi in pbase), full lines
        float* p0 = pbase + (size_t)t0 * 32;
        float* p1 = p0 + 32;
#pragma unroll
        for (int r = 0; r < 16; ++r) {
            size_t ro = (size_t)((r & 3) + 8 * (r >> 2)) * N_WO;
            p0[ro] = acc0[r] + bj0;
            p1[ro] = acc1[r] + bj1;
        }
    }
}

// Correctness fallback if d_ws is too small for the transposed panels.
__global__ __launch_bounds__(256) void naive_kernel(const float* __restrict__ x,
                                                    const float* __restrict__ wgt,
                                                    const float* __restrict__ bias,
                                                    float* __restrict__ out) {
    size_t idx = (size_t)blockIdx.x * 256 + threadIdx.x;
    if (idx >= OUT_TOTAL) return;
    int n    = (int)(idx >> 13);
    int ncol = (int)(idx & 8191);
    float s = 0.f;
    for (int i = 0; i < K_DIM; ++i)
        s += x[(size_t)i * N_X + n] * wgt[(size_t)i * N_WO + ncol];
    out[idx] = s + 128.0f * bias[ncol & 127];
}

extern "C" void kernel_launch(void* const* d_in, const int* in_sizes, int n_in,
                              void* d_out, int out_size, void* d_ws, size_t ws_size,
                              hipStream_t stream) {
    const float* x    = (const float*)d_in[0];   // [128][8192]
    const float* wgt  = (const float*)d_in[1];   // [128][64*128]
    const float* bias = (const float*)d_in[2];   // [128]
    float* out = (float*)d_out;

    if (ws_size >= 4u * 1024u * 1024u) {
        uint4* wsA = (uint4*)d_ws;                    // 2 MiB: x^T frag bf16
        uint4* wsB = wsA + CHUNKS_PER_PANEL;          // 2 MiB: W   frag bf16
        prep_frag2<<<1024, 256, 0, stream>>>(x, wgt, wsA);
        gemm_sweep32<<<256, 512, 0, stream>>>((const short8*)wsA,
                                              (const short8*)wsB, bias, out);
    } else {
        naive_kernel<<<(unsigned)((OUT_TOTAL + 255) / 256), 256, 0, stream>>>(
            x, wgt, bias, out);
    }
}

// Round 11
// 72.479 us; speedup vs baseline: 1.3415x; 1.0753x over previous
//
#include <hip/hip_runtime.h>
#include <hip/hip_bf16.h>
#include <stdint.h>

#define K_DIM 128
#define N_X   8192      // columns of x (the "n" / M dimension)
#define N_WO  8192      // 64*128 flattened (w,o) -> GEMM N dimension
#define OUT_TOTAL (8192UL * 64UL * 128UL)
#define CHUNKS_PER_PANEL 131072   // (8192/16 tiles) * 4 ksteps * 64 lanes

typedef __attribute__((ext_vector_type(8))) short short8;   // 8 bf16 = 4 VGPR
typedef __attribute__((ext_vector_type(4))) float f32x4;

__device__ inline unsigned short f2bf(float f) {
    union { float f; unsigned u; } v; v.f = f;
    unsigned u = v.u;
    u += 0x7fffu + ((u >> 16) & 1u);   // round-to-nearest-even
    return (unsigned short)(u >> 16);
}

// Transpose+convert BOTH panels P[128][8192] f32 (k-major, inner contiguous)
// into MFMA fragment-linear bf16 blocks. Chunk cc = ((t*4 + ks)*64 + l):
//   elem j (0..7): P[ks*32 + (l>>4)*8 + j][t*16 + (l&15)]
__global__ __launch_bounds__(256) void prep_frag2(const float* __restrict__ X,
                                                  const float* __restrict__ W,
                                                  uint4* __restrict__ Q) {
    int c  = blockIdx.x * 256 + threadIdx.x;   // 0 .. 262143
    int cc = c & (CHUNKS_PER_PANEL - 1);
    const float* P = (c >= CHUNKS_PER_PANEL) ? W : X;
    int l  = cc & 63;
    int ks = (cc >> 6) & 3;
    int t  = cc >> 8;
    int m  = t * 16 + (l & 15);
    int k0 = ks * 32 + ((l >> 4) << 3);
    const float* p = P + (size_t)k0 * N_X + m;
    unsigned short h[8];
#pragma unroll
    for (int j = 0; j < 8; ++j) h[j] = f2bf(p[(size_t)j * N_X]);
    uint4 q;
    q.x = (unsigned)h[0] | ((unsigned)h[1] << 16);
    q.y = (unsigned)h[2] | ((unsigned)h[3] << 16);
    q.z = (unsigned)h[4] | ((unsigned)h[5] << 16);
    q.w = (unsigned)h[6] | ((unsigned)h[7] << 16);
    Q[c] = q;
}

// Row-slab sweep GEMM, 64-row slab / half-wo variant (r5 structure, B-read
// volume halved). Block = 64 output rows (n) x 4096 wo (one half), 512
// threads = 8 waves, grid 256 = 128 slabs x 2 halves. x fragments for all 4
// row-tiles live in REGISTERS (zero x re-reads); W streams from the bf16
// fragment panel: 1 MiB slice per block, 256 MiB total chip-wide (was 512).
// Halves are XCD-segregated (half = xcd&1) so each XCD L2 carries only its
// 1 MiB B-slice. No LDS, no barriers: stores flow continuously.
// Operand-SWAPPED mfma: acc = mfma(Wfrag, xfrag) => D[wo][n]; lane holds 4
// consecutive wo at one n -> contiguous dwordx4 stores.
__global__ __launch_bounds__(512, 2) void gemm_sweep(const short8* __restrict__ A,
                                                     const short8* __restrict__ B,
                                                     const float* __restrict__ bias,
                                                     float* __restrict__ out) {
    int bid  = blockIdx.x;
    int xcd  = bid & 7;
    int slot = bid >> 3;               // 0..31
    int half = xcd & 1;
    int slab = (xcd >> 1) * 32 + slot; // 0..127, bijective with (xcd,slot)
    int n0   = slab * 64;

    int tid  = threadIdx.x;
    int lane = tid & 63;
    int w    = tid >> 6;               // 0..7
    int cl = lane & 15, rg = (lane >> 4) << 2;

    // x fragments for this block's 4 row-tiles, all 4 K-steps (VGPR-resident)
    short8 xf[4][4];
#pragma unroll
    for (int i = 0; i < 4; ++i)
#pragma unroll
        for (int ks = 0; ks < 4; ++ks)
            xf[i][ks] = A[(size_t)((slab * 4 + i) * 4 + ks) * 64 + lane];

    // bias: tile index (half*256 + it*32 + w*4 + j) mod 8 = (w*4+j)&7 —
    // iteration-invariant -> hoist 4 premultiplied float4s.
    f32x4 bvs[4];
#pragma unroll
    for (int j = 0; j < 4; ++j) {
        const f32x4 bv = *(const f32x4*)(bias + ((((w * 4 + j) & 7) << 4) + rg));
        bvs[j].x = 128.0f * bv.x;  bvs[j].y = 128.0f * bv.y;
        bvs[j].z = 128.0f * bv.z;  bvs[j].w = 128.0f * bv.w;
    }

    // per-lane output row bases (4 row-tiles, row cl within each)
    float* po[4];
#pragma unroll
    for (int i = 0; i < 4; ++i)
        po[i] = out + (size_t)(n0 + i * 16 + cl) * N_WO;

    int tbase = half * 256;            // first wo-tile of this half

    for (int it = 0; it < 8; ++it) {
        int tj0 = tbase + it * 32 + w * 4;   // wave's 4 wo-tiles this iter
        short8 wf[4][4];
#pragma unroll
        for (int j = 0; j < 4; ++j)
#pragma unroll
            for (int ks = 0; ks < 4; ++ks)
                wf[j][ks] = B[(size_t)((tj0 + j) * 4 + ks) * 64 + lane];

        f32x4 acc[4][4] = {};
#pragma unroll
        for (int ks = 0; ks < 4; ++ks)
#pragma unroll
            for (int i = 0; i < 4; ++i)
#pragma unroll
                for (int j = 0; j < 4; ++j)
                    acc[i][j] = __builtin_amdgcn_mfma_f32_16x16x32_bf16(
                        wf[j][ks], xf[i][ks], acc[i][j], 0, 0, 0); // D[wo][n]

        // stores: col(lane&15)=n within tile i, row((lane>>4)*4+reg)=wo
#pragma unroll
        for (int j = 0; j < 4; ++j) {
            int wo = (tj0 + j) * 16 + rg;
#pragma unroll
            for (int i = 0; i < 4; ++i) {
                f32x4 v = acc[i][j];
                v.x += bvs[j].x; v.y += bvs[j].y;
                v.z += bvs[j].z; v.w += bvs[j].w;
                *(f32x4*)(po[i] + wo) = v;
            }
        }
    }
}

// Correctness fallback if d_ws is too small for the transposed panels.
__global__ __launch_bounds__(256) void naive_kernel(const float* __restrict__ x,
                                                    const float* __restrict__ wgt,
                                                    const float* __restrict__ bias,
                                                    float* __restrict__ out) {
    size_t idx = (size_t)blockIdx.x * 256 + threadIdx.x;
    if (idx >= OUT_TOTAL) return;
    int n    = (int)(idx >> 13);
    int ncol = (int)(idx & 8191);
    float s = 0.f;
    for (int i = 0; i < K_DIM; ++i)
        s += x[(size_t)i * N_X + n] * wgt[(size_t)i * N_WO + ncol];
    out[idx] = s + 128.0f * bias[ncol & 127];
}

extern "C" void kernel_launch(void* const* d_in, const int* in_sizes, int n_in,
                              void* d_out, int out_size, void* d_ws, size_t ws_size,
                              hipStream_t stream) {
    const float* x    = (const float*)d_in[0];   // [128][8192]
    const float* wgt  = (const float*)d_in[1];   // [128][64*128]
    const float* bias = (const float*)d_in[2];   // [128]
    float* out = (float*)d_out;

    if (ws_size >= 4u * 1024u * 1024u) {
        uint4* wsA = (uint4*)d_ws;                    // 2 MiB: x^T frag bf16
        uint4* wsB = wsA + CHUNKS_PER_PANEL;          // 2 MiB: W   frag bf16
        prep_frag2<<<1024, 256, 0, stream>>>(x, wgt, wsA);
        gemm_sweep<<<256, 512, 0, stream>>>((const short8*)wsA,
                                            (const short8*)wsB, bias, out);
    } else {
        naive_kernel<<<(unsigned)((OUT_TOTAL + 255) / 256), 256, 0, stream>>>(
            x, wgt, bias, out);
    }
}